// Round 3
// baseline (228.054 us; speedup 1.0000x reference)
//
#include <hip/hip_runtime.h>

// DataPreprocessor: interleave even/odd row planes then extract 16x16 patches.
// out[b, z1*32+z2, p*16+q] = in[b, parity, k*512 + c],
//   r = 16*z1 + p, c = 16*z2 + q, parity = r&1, k = r>>1.
//
// Block = one (b, z1) slab (256 threads = 4 waves). The permutation is closed
// under column-quarters: output z2 in [8w,8w+8) depends only on input
// col4 in [32w,32w+32). So wave w stages its own quarter through a
// WAVE-PRIVATE LDS region — no __syncthreads() anywhere, no inter-wave
// sharing (within-wave LDS ordering is lgkmcnt-enforced by the compiler).
//
//   reads : per wave, 16 segments of 512 B (2 per instruction), fully covered
//   writes: per wave, 8 KiB contiguous; per block, 32 KiB contiguous
//
// LDS: per wave 16 rows x 33 float4 (32 + 1 pad -> uniform bank spread in
// both phases). 4 waves x 528 x 16 B = 33,792 B -> 4 blocks/CU, 16 waves/CU,
// 8 outstanding 16B loads/lane: ample latency hiding.

#define ROW4 33              // float4 stride per local R-row
#define WREG (16 * ROW4)     // float4s per wave-private region

__global__ __launch_bounds__(256) void DataPreprocessor_60739427500336_kernel(
    const float4* __restrict__ in, float4* __restrict__ out) {
    __shared__ float4 lds[4 * WREG];  // 33,792 B

    const int tid = threadIdx.x;
    const int w   = tid >> 6;     // wave 0..3 -> column-quarter
    const int L   = tid & 63;     // lane
    const int b   = blockIdx.x >> 4;   // 0..255
    const int z1  = blockIdx.x & 15;   // 0..15

    const int in_base = (b << 15) + (z1 << 10);  // float4 idx of slab in plane0
    const int wbase   = w * WREG;

    // ---- stage: global (512B segments) -> wave-private LDS ----
    // idx = j*64 + L in [0,512): pl = idx>>8, k = (idx>>5)&7, cc = idx&31
    // global float4: b*32768 + pl*16384 + (8*z1+k)*128 + w*32 + cc
    // lds row r = 2k+pl (local R-row), col cc
    #pragma unroll
    for (int j = 0; j < 8; ++j) {
        int idx = (j << 6) + L;
        int pl  = idx >> 8;
        int k   = (idx >> 5) & 7;
        int cc  = idx & 31;
        int r   = (k << 1) + pl;
        lds[wbase + r * ROW4 + cc] =
            in[in_base + (pl << 14) + (k << 7) + (w << 5) + cc];
    }

    // (no barrier: each wave reads only what it wrote)

    // ---- permute: wave-private LDS -> global (contiguous) ----
    // o4l = j*64 + L in [0,512): z2l = j, p = L>>2, q4 = L&3
    // lds read: row p, col 4*j + q4  (global col4 = w*32 + 4*j + q4)
    // out float4: b*32768 + z1*2048 + w*512 + o4l
    const int out_base = (b << 15) + (z1 << 11) + (w << 9);
    #pragma unroll
    for (int j = 0; j < 8; ++j) {
        int p  = L >> 2;
        int q4 = L & 3;
        out[out_base + (j << 6) + L] =
            lds[wbase + p * ROW4 + (j << 2) + q4];
    }
}

extern "C" void kernel_launch(void* const* d_in, const int* in_sizes, int n_in,
                              void* d_out, int out_size, void* d_ws, size_t ws_size,
                              hipStream_t stream) {
    const float4* in = (const float4*)d_in[0];
    float4* out = (float4*)d_out;
    // 256 batches x 16 z1-slabs
    DataPreprocessor_60739427500336_kernel<<<4096, 256, 0, stream>>>(in, out);
}